// Round 1
// baseline (2334.661 us; speedup 1.0000x reference)
//
#include <hip/hip_runtime.h>
#include <cstdint>
#include <cstddef>

// Problem constants (fixed by reference)
#define CB    4096          // codebook size C
#define DD    512           // dim D (= K of the GEMM)
#define M_TOK 32768         // B*N tokens
#define DECAY_F 0.8f
#define OMD_F   0.2f        // 1 - DECAY
#define EPS_F   1e-5f

// Output layout (flat float32, reference return order)
#define OFF_QUANT ((size_t)0)
#define SZ_QUANT  ((size_t)M_TOK * DD)            // 16777216
#define OFF_IND   (OFF_QUANT + SZ_QUANT)
#define SZ_IND    ((size_t)M_TOK)                 // 32768
#define OFF_DIST  (OFF_IND + SZ_IND)
#define SZ_DIST   ((size_t)M_TOK * CB)            // 134217728
#define OFF_NC    (OFF_DIST + SZ_DIST)
#define SZ_NC     ((size_t)CB)
#define OFF_AVG   (OFF_NC + SZ_NC)
#define SZ_AVG    ((size_t)CB * DD)
#define OFF_NEMB  (OFF_AVG + SZ_AVG)

// ---------------------------------------------------------------- K0: init
// avg_out = 0.8 * embed_avg ; zero bins ; zero tot
__global__ __launch_bounds__(256) void k_init(const float* __restrict__ eavg,
                                              float* __restrict__ avg_out,
                                              int* __restrict__ bins,
                                              float* __restrict__ tot) {
  size_t id = (size_t)blockIdx.x * 256 + threadIdx.x;   // 0..524287 (float4 units)
  float4 v = *(const float4*)(eavg + id * 4);
  float4 o;
  o.x = v.x * DECAY_F; o.y = v.y * DECAY_F; o.z = v.z * DECAY_F; o.w = v.w * DECAY_F;
  *(float4*)(avg_out + id * 4) = o;
  if (id < CB) bins[id] = 0;
  if (id == CB) *tot = 0.0f;
}

// ---------------------------------------------------------------- K1: GEMM
// dist[m][c] = sum_k X[m][k] * E[c][k]   (M=32768, N=4096, K=512; both K-major)
#define BM 128
#define BN 128
#define BK 16

__global__ __launch_bounds__(256) void k_dist_gemm(const float* __restrict__ X,
                                                   const float* __restrict__ E,
                                                   float* __restrict__ dist) {
  __shared__ float As[BK][BM + 4];   // transposed in LDS: As[k][m]
  __shared__ float Bs[BK][BN + 4];
  const int tid = threadIdx.x;
  const int bn  = blockIdx.x;        // 0..31
  const int bm  = blockIdx.y;        // 0..255
  const int tr  = tid >> 4;          // 0..15
  const int tc  = tid & 15;          // 0..15

  float acc[8][8];
#pragma unroll
  for (int i = 0; i < 8; ++i)
#pragma unroll
    for (int j = 0; j < 8; ++j) acc[i][j] = 0.0f;

  const float* Xb = X + (size_t)bm * BM * DD;
  const float* Eb = E + (size_t)bn * BN * DD;

  for (int kt = 0; kt < DD; kt += BK) {
#pragma unroll
    for (int l = 0; l < 2; ++l) {
      int linear = tid + l * 256;          // 0..511
      int row = linear >> 2;               // 0..127
      int k4  = (linear & 3) << 2;         // 0,4,8,12
      float4 va = *(const float4*)(Xb + (size_t)row * DD + kt + k4);
      As[k4 + 0][row] = va.x; As[k4 + 1][row] = va.y;
      As[k4 + 2][row] = va.z; As[k4 + 3][row] = va.w;
      float4 vb = *(const float4*)(Eb + (size_t)row * DD + kt + k4);
      Bs[k4 + 0][row] = vb.x; Bs[k4 + 1][row] = vb.y;
      Bs[k4 + 2][row] = vb.z; Bs[k4 + 3][row] = vb.w;
    }
    __syncthreads();
#pragma unroll
    for (int k = 0; k < BK; ++k) {
      float a[8], b[8];
      *(float4*)(a)     = *(const float4*)&As[k][tr * 4];
      *(float4*)(a + 4) = *(const float4*)&As[k][tr * 4 + 64];
      *(float4*)(b)     = *(const float4*)&Bs[k][tc * 4];
      *(float4*)(b + 4) = *(const float4*)&Bs[k][tc * 4 + 64];
#pragma unroll
      for (int i = 0; i < 8; ++i)
#pragma unroll
        for (int j = 0; j < 8; ++j) acc[i][j] = fmaf(a[i], b[j], acc[i][j]);
    }
    __syncthreads();
  }

#pragma unroll
  for (int i = 0; i < 8; ++i) {
    int row = bm * BM + ((i < 4) ? (tr * 4 + i) : (tr * 4 + 64 + (i - 4)));
    float* drow = dist + (size_t)row * CB + bn * BN;
    float4 o0, o1;
    o0.x = acc[i][0]; o0.y = acc[i][1]; o0.z = acc[i][2]; o0.w = acc[i][3];
    o1.x = acc[i][4]; o1.y = acc[i][5]; o1.z = acc[i][6]; o1.w = acc[i][7];
    *(float4*)(drow + tc * 4)      = o0;
    *(float4*)(drow + tc * 4 + 64) = o1;
  }
}

// ---------------------------------------------------------------- K2: argmax rows (+histogram)
__global__ __launch_bounds__(256) void k_argmax(const float* __restrict__ dist,
                                                float* __restrict__ ind_f,
                                                int* __restrict__ idx_ws,
                                                int* __restrict__ bins) {
  const int row = blockIdx.x;
  const float* p = dist + (size_t)row * CB;
  const int tid = threadIdx.x;
  float best = -3.402823466e38f;
  int bi = 0;
#pragma unroll
  for (int it = 0; it < 4; ++it) {
    int j4 = (tid + it * 256) << 2;      // ascending within thread -> strict > keeps first
    float4 v = *(const float4*)(p + j4);
    if (v.x > best) { best = v.x; bi = j4; }
    if (v.y > best) { best = v.y; bi = j4 + 1; }
    if (v.z > best) { best = v.z; bi = j4 + 2; }
    if (v.w > best) { best = v.w; bi = j4 + 3; }
  }
  // wave reduce (64 lanes), first-occurrence tie-break
  for (int off = 32; off; off >>= 1) {
    float ov = __shfl_down(best, off);
    int   oi = __shfl_down(bi, off);
    if (ov > best || (ov == best && oi < bi)) { best = ov; bi = oi; }
  }
  __shared__ float sv[4];
  __shared__ int   si[4];
  int wid = tid >> 6;
  if ((tid & 63) == 0) { sv[wid] = best; si[wid] = bi; }
  __syncthreads();
  if (tid == 0) {
#pragma unroll
    for (int w = 1; w < 4; ++w)
      if (sv[w] > best || (sv[w] == best && si[w] < bi)) { best = sv[w]; bi = si[w]; }
    ind_f[row]  = (float)bi;
    idx_ws[row] = bi;
    atomicAdd(&bins[bi], 1);
  }
}

// ---------------------------------------------------------------- K3: quantize gather + embed_sum scatter
__global__ __launch_bounds__(256) void k_quant_scatter(const float* __restrict__ X,
                                                       const float* __restrict__ E,
                                                       const int* __restrict__ idx_ws,
                                                       float* __restrict__ quant,
                                                       float* __restrict__ avg) {
  size_t id = (size_t)blockIdx.x * 256 + threadIdx.x;   // 0..4194303 (float4 units)
  int n  = (int)(id >> 7);
  int d4 = (int)(id & 127) << 2;
  int c  = idx_ws[n];
  float4 e = *(const float4*)(E + (size_t)c * DD + d4);
  *(float4*)(quant + (size_t)n * DD + d4) = e;
  float4 xv = *(const float4*)(X + (size_t)n * DD + d4);
  float* dst = avg + (size_t)c * DD + d4;
  atomicAdd(dst + 0, OMD_F * xv.x);
  atomicAdd(dst + 1, OMD_F * xv.y);
  atomicAdd(dst + 2, OMD_F * xv.z);
  atomicAdd(dst + 3, OMD_F * xv.w);
}

// ---------------------------------------------------------------- K4: new_cluster + total
__global__ __launch_bounds__(256) void k_cluster(const float* __restrict__ cs,
                                                 const int* __restrict__ bins,
                                                 float* __restrict__ nc_out,
                                                 float* __restrict__ tot) {
  int c = blockIdx.x * 256 + threadIdx.x;   // grid 16 -> 4096
  float nc = DECAY_F * cs[c] + OMD_F * (float)bins[c];
  nc_out[c] = nc;
  float s = nc;
  for (int off = 32; off; off >>= 1) s += __shfl_down(s, off);
  if ((threadIdx.x & 63) == 0) atomicAdd(tot, s);
}

// ---------------------------------------------------------------- K5: laplace-smooth + l2norm rows
__global__ __launch_bounds__(128) void k_norm(const float* __restrict__ avg,
                                              const float* __restrict__ nc,
                                              const float* __restrict__ tot,
                                              float* __restrict__ out) {
  int c = blockIdx.x;
  int tid = threadIdx.x;                     // 128 threads, D=512 -> float4 each
  const float* row = avg + (size_t)c * DD;
  float4 v = *(const float4*)(row + tid * 4);
  float ss = v.x * v.x + v.y * v.y + v.z * v.z + v.w * v.w;
  for (int off = 32; off; off >>= 1) ss += __shfl_down(ss, off);
  __shared__ float s2[2];
  if ((tid & 63) == 0) s2[tid >> 6] = ss;
  __syncthreads();
  float sumsq = s2[0] + s2[1];
  float t = *tot;
  float sm = (nc[c] + EPS_F) / (t + (float)CB * EPS_F) * t;   // > 0
  float nrm = sqrtf(sumsq) / sm;             // ||avg/sm||
  float denom = fmaxf(nrm, 1e-12f);
  float scale = 1.0f / (sm * denom);
  float4 o;
  o.x = v.x * scale; o.y = v.y * scale; o.z = v.z * scale; o.w = v.w * scale;
  *(float4*)(out + (size_t)c * DD + tid * 4) = o;
}

// ---------------------------------------------------------------- launch
extern "C" void kernel_launch(void* const* d_in, const int* in_sizes, int n_in,
                              void* d_out, int out_size, void* d_ws, size_t ws_size,
                              hipStream_t stream) {
  const float* x     = (const float*)d_in[0];   // (8,4096,512)
  const float* embed = (const float*)d_in[1];   // (1,4096,512)
  const float* cs    = (const float*)d_in[2];   // (1,4096)
  const float* eavg  = (const float*)d_in[3];   // (1,4096,512)

  float* out    = (float*)d_out;
  float* quant  = out + OFF_QUANT;
  float* indf   = out + OFF_IND;
  float* dist   = out + OFF_DIST;
  float* ncout  = out + OFF_NC;
  float* avgout = out + OFF_AVG;
  float* nemb   = out + OFF_NEMB;

  int*   idx_ws = (int*)d_ws;                 // 32768 ints
  int*   bins   = idx_ws + M_TOK;             // 4096 ints
  float* tot    = (float*)(bins + CB);        // 1 float

  k_init<<<dim3(2048), dim3(256), 0, stream>>>(eavg, avgout, bins, tot);
  k_dist_gemm<<<dim3(CB / BN, M_TOK / BM), dim3(256), 0, stream>>>(x, embed, dist);
  k_argmax<<<dim3(M_TOK), dim3(256), 0, stream>>>(dist, indf, idx_ws, bins);
  k_quant_scatter<<<dim3(16384), dim3(256), 0, stream>>>(x, embed, idx_ws, quant, avgout);
  k_cluster<<<dim3(16), dim3(256), 0, stream>>>(cs, bins, ncout, tot);
  k_norm<<<dim3(CB), dim3(128), 0, stream>>>(avgout, ncout, tot, nemb);
}